// Round 4
// baseline (2338.774 us; speedup 1.0000x reference)
//
#include <hip/hip_runtime.h>
#include <hip/hip_bf16.h>

typedef __hip_bfloat16 bf16;
typedef __attribute__((ext_vector_type(8))) short s16x8;   // 8 bf16 (4 VGPRs) MFMA frag
typedef __attribute__((ext_vector_type(4))) float f32x4;   // MFMA accumulator

#define NN 1024      // nodes
#define NE 30720     // edges
#define CS 32
#define CV 8
#define CZ 128
#define INS 28
#define INV 37
#define NRDIM 139    // 28 + 3*37
#define INZ 1664
#define WN 1664      // WEIGHT_NUMEL
#define NL 4

__device__ __forceinline__ float b2f(bf16 x) { return __bfloat162float(x); }
__device__ __forceinline__ bf16 f2b(float x) { return __float2bfloat16(x); }

// ---------------------------------------------------------------------------
// Skinny MFMA GEMM, N=128 fixed:  C[M,128] = act(A[M,K] @ Bt[128,K]^T + bias)
// Tile M=64 -> grid M/64 (480 for edge tensors) => ~2 blocks/CU (vs 1 at 128).
// AF32: A is fp32 (converted in staging).  GATHER: A row e is the concat
// [a_b[dst[e]] | a_b[src[e]] | ef_b[e]] (K=384) -- replaces build_ein.
// 4 waves; wave w covers all 64 rows x cols [w*32, w*32+32): acc[4][2].
// ---------------------------------------------------------------------------
template<int RELU, int AF32, int GATHER>
__global__ __launch_bounds__(256)
void gemm64(const void* __restrict__ Ap, const bf16* __restrict__ Bt,
            const float* __restrict__ bias, bf16* __restrict__ Cp,
            int M, int K,
            const bf16* __restrict__ g_a, const bf16* __restrict__ g_ef,
            const int* __restrict__ g_ei)
{
    __shared__ __align__(16) bf16 la[64 * 40];
    __shared__ __align__(16) bf16 lb[128 * 40];
    const int bm = blockIdx.x * 64;
    const int tid = threadIdx.x;
    const int lane = tid & 63;
    const int wv = tid >> 6;
    const int lr = tid >> 1;          // B loader row 0..127 (A loader: 0..63 for tid<128)
    const int lc = (tid & 1) * 16;
    const int l15 = lane & 15;
    const int quad = lane >> 4;
    f32x4 acc[4][2] = {};
    const bf16* gb = Bt + (size_t)lr * K + lc;
    const bf16*  ga16 = (const bf16*) Ap + (size_t)(bm + lr) * K + lc;
    const float* ga32 = (const float*)Ap + (size_t)(bm + lr) * K + lc;
    int gdst = 0, gsrc = 0, grow = 0;
    if (GATHER && tid < 128) {
        grow = bm + lr;
        gdst = g_ei[grow];
        gsrc = g_ei[NE + grow];
    }
    for (int k0 = 0; k0 < K; k0 += 32) {
        union { bf16 h[16]; float4 q[2]; } pa;
        if (tid < 128) {
            if (AF32) {
                float4 f0 = *(const float4*)(ga32 + k0);
                float4 f1 = *(const float4*)(ga32 + k0 + 4);
                float4 f2 = *(const float4*)(ga32 + k0 + 8);
                float4 f3 = *(const float4*)(ga32 + k0 + 12);
                pa.h[0]=f2b(f0.x); pa.h[1]=f2b(f0.y); pa.h[2]=f2b(f0.z); pa.h[3]=f2b(f0.w);
                pa.h[4]=f2b(f1.x); pa.h[5]=f2b(f1.y); pa.h[6]=f2b(f1.z); pa.h[7]=f2b(f1.w);
                pa.h[8]=f2b(f2.x); pa.h[9]=f2b(f2.y); pa.h[10]=f2b(f2.z); pa.h[11]=f2b(f2.w);
                pa.h[12]=f2b(f3.x); pa.h[13]=f2b(f3.y); pa.h[14]=f2b(f3.z); pa.h[15]=f2b(f3.w);
            } else if (GATHER) {
                int kk = k0 + lc;
                const bf16* src;
                if (kk < 128)      src = g_a  + (size_t)gdst * CZ + kk;
                else if (kk < 256) src = g_a  + (size_t)gsrc * CZ + (kk - 128);
                else               src = g_ef + (size_t)grow * CZ + (kk - 256);
                pa.q[0] = *(const float4*)src;
                pa.q[1] = *(const float4*)(src + 8);
            } else {
                pa.q[0] = *(const float4*)(ga16 + k0);
                pa.q[1] = *(const float4*)(ga16 + k0 + 8);
            }
        }
        float4 b0 = *(const float4*)(gb + k0);
        float4 b1 = *(const float4*)(gb + k0 + 8);
        __syncthreads();
        if (tid < 128) {
            *(float4*)&la[lr * 40 + lc]     = pa.q[0];
            *(float4*)&la[lr * 40 + lc + 8] = pa.q[1];
        }
        *(float4*)&lb[lr * 40 + lc]     = b0;
        *(float4*)&lb[lr * 40 + lc + 8] = b1;
        __syncthreads();
        s16x8 af[4], bfr[2];
#pragma unroll
        for (int mi = 0; mi < 4; mi++)
            af[mi] = *(const s16x8*)&la[(mi * 16 + l15) * 40 + quad * 8];
#pragma unroll
        for (int ni = 0; ni < 2; ni++)
            bfr[ni] = *(const s16x8*)&lb[(wv * 32 + ni * 16 + l15) * 40 + quad * 8];
#pragma unroll
        for (int mi = 0; mi < 4; mi++)
#pragma unroll
            for (int ni = 0; ni < 2; ni++)
                acc[mi][ni] = __builtin_amdgcn_mfma_f32_16x16x32_bf16(af[mi], bfr[ni], acc[mi][ni], 0, 0, 0);
    }
    // epilogue: C/D layout col=lane&15, row=quad*4+reg [m89/m91 verified]
#pragma unroll
    for (int ni = 0; ni < 2; ni++) {
        const int col = wv * 32 + ni * 16 + l15;
        const float bv = bias[col];
#pragma unroll
        for (int mi = 0; mi < 4; mi++) {
            const int row0 = bm + mi * 16 + quad * 4;
#pragma unroll
            for (int r = 0; r < 4; r++) {
                float v = acc[mi][ni][r] + bv;
                if (RELU) v = fmaxf(v, 0.f);
                Cp[(size_t)(row0 + r) * CZ + col] = f2b(v);
            }
        }
    }
}

// ---------------------------------------------------------------------------
// Fused fc2 GEMM + tensor product + scatter.  Block = 64 edges (grid 480).
// A (h1, K=128) is LDS-staged once then held in registers (16 frags/wave);
// B (fc_w2t [1664,128]) is streamed per-lane from global (L2-resident).
// Per 128-col chunk: MFMA -> per-value TP decode (wave-uniform region branch,
// boundaries 1024/1280/1344/1600 all multiples of 16) -> LDS f32 atomics into
// per-edge out[56]; final global atomic scatter pre-scaled by 1/cnt[src].
// ---------------------------------------------------------------------------
__global__ __launch_bounds__(256)
void fc2_tp(const bf16* __restrict__ h1, const bf16* __restrict__ w2t,
            const float* __restrict__ b2, const int* __restrict__ ei,
            const float* __restrict__ edge_vecs,
            const float* __restrict__ xs, const float* __restrict__ xv,
            const float* __restrict__ icnt,
            float* __restrict__ ags, float* __restrict__ agv)
{
    __shared__ __align__(16) bf16 la[64 * 136];   // stride 136: 16B-aligned rows, 2-way banks
    __shared__ bf16 s_xs[64][32];
    __shared__ bf16 s_xv[64][24];
    __shared__ bf16 s_cr[64][24];
    __shared__ bf16 s_y4[64][8];
    __shared__ float s_shv[64][3];
    __shared__ float s_out[64][56];
    __shared__ float s_ic[64];
    __shared__ int s_dst[64], s_src[64];
    const int bm = blockIdx.x * 64;
    const int t = threadIdx.x;
    const int lane = t & 63;
    const int wv = t >> 6;
    const int l15 = lane & 15;
    const int quad = lane >> 4;

    if (t < 64) {
        int e = bm + t;
        int d = ei[e], s = ei[NE + e];
        s_dst[t] = d; s_src[t] = s; s_ic[t] = icnt[s];
        float vx = edge_vecs[e * 3 + 0];
        float vy = edge_vecs[e * 3 + 1];
        float vz = edge_vecs[e * 3 + 2];
        float sc = 1.7320508075688772f / (sqrtf(vx * vx + vy * vy + vz * vz) + 1e-8f);
        s_shv[t][0] = vx * sc; s_shv[t][1] = vy * sc; s_shv[t][2] = vz * sc;
    }
    __syncthreads();
    {   // gather xs/xv of dst (bf16 coeffs)
        int eL = t >> 2;
        int d = s_dst[eL];
        int i0 = (t & 3) * 8;
        for (int i = 0; i < 8; i++) s_xs[eL][i0 + i] = f2b(xs[d * CS + i0 + i]);
        int j0 = (t & 3) * 6;
        for (int i = 0; i < 6; i++) s_xv[eL][j0 + i] = f2b(xv[d * 24 + j0 + i]);
    }
    {   // stage h1 tile: 64 x 128
        int r = t >> 2, c0 = (t & 3) * 32;
        const float4* s4 = (const float4*)(h1 + (size_t)(bm + r) * CZ + c0);
        float4* d4 = (float4*)&la[r * 136 + c0];
        d4[0] = s4[0]; d4[1] = s4[1]; d4[2] = s4[2]; d4[3] = s4[3];
    }
    for (int i = t; i < 64 * 56; i += 256) ((float*)s_out)[i] = 0.f;
    __syncthreads();
    if (t < 64) {   // y4 (dot with sh_v) and cross products
        float h0 = s_shv[t][0], hv1 = s_shv[t][1], h2 = s_shv[t][2];
        for (int i = 0; i < 8; i++) {
            float x0 = b2f(s_xv[t][i * 3 + 0]);
            float x1 = b2f(s_xv[t][i * 3 + 1]);
            float x2 = b2f(s_xv[t][i * 3 + 2]);
            s_y4[t][i] = f2b(x0 * h0 + x1 * hv1 + x2 * h2);
            s_cr[t][i * 3 + 0] = f2b(x1 * h2 - x2 * hv1);
            s_cr[t][i * 3 + 1] = f2b(x2 * h0 - x0 * h2);
            s_cr[t][i * 3 + 2] = f2b(x0 * hv1 - x1 * h0);
        }
    }
    __syncthreads();

    s16x8 af[4][4];   // whole A tile in registers: af[m-subtile][k-chunk]
#pragma unroll
    for (int mi = 0; mi < 4; mi++)
#pragma unroll
        for (int kk = 0; kk < 4; kk++)
            af[mi][kk] = *(const s16x8*)&la[(mi * 16 + l15) * 136 + kk * 32 + quad * 8];

    for (int c = 0; c < 13; c++) {
        const int nbase = c * 128 + wv * 32;
#pragma unroll
        for (int ni = 0; ni < 2; ni++) {
            const int n = nbase + ni * 16 + l15;     // this lane's weight column
            f32x4 acc[4] = {};
#pragma unroll
            for (int kk = 0; kk < 4; kk++) {
                s16x8 bfr = *(const s16x8*)(w2t + (size_t)n * CZ + kk * 32 + quad * 8);
#pragma unroll
                for (int mi = 0; mi < 4; mi++)
                    acc[mi] = __builtin_amdgcn_mfma_f32_16x16x32_bf16(af[mi][kk], bfr, acc[mi], 0, 0, 0);
            }
            const float bv = b2[n];
            const int n16 = nbase + ni * 16;         // wave-uniform region selector
#pragma unroll
            for (int mi = 0; mi < 4; mi++) {
#pragma unroll
                for (int r = 0; r < 4; r++) {
                    const int row = mi * 16 + quad * 4 + r;   // edge within block
                    const float v = acc[mi][r] + bv;
                    if (n16 < 1024) {                 // w1: 0e x 0e -> 0e
                        int i = n >> 5, j = n & 31;
                        atomicAdd(&s_out[row][j], 0.125f * b2f(s_xs[row][i]) * v);
                    } else if (n16 < 1280) {          // w2: 0e x 1e -> 1e
                        int d = n - 1024; int i = d >> 3, j = d & 7;
                        float cs = 0.10206207261596575f * b2f(s_xs[row][i]) * v;
                        atomicAdd(&s_out[row][32 + j * 3 + 0], cs * s_shv[row][0]);
                        atomicAdd(&s_out[row][32 + j * 3 + 1], cs * s_shv[row][1]);
                        atomicAdd(&s_out[row][32 + j * 3 + 2], cs * s_shv[row][2]);
                    } else if (n16 < 1344) {          // w3: 1e x 0e -> 1e
                        int d = n - 1280; int i = d >> 3, j = d & 7;
                        float sv = 0.2041241452319315f * v;
                        atomicAdd(&s_out[row][32 + j * 3 + 0], sv * b2f(s_xv[row][i * 3 + 0]));
                        atomicAdd(&s_out[row][32 + j * 3 + 1], sv * b2f(s_xv[row][i * 3 + 1]));
                        atomicAdd(&s_out[row][32 + j * 3 + 2], sv * b2f(s_xv[row][i * 3 + 2]));
                    } else if (n16 < 1600) {          // w4: 1e . 1e -> 0e
                        int d = n - 1344; int i = d >> 5, j = d & 31;
                        atomicAdd(&s_out[row][j], 0.14433756729740643f * b2f(s_y4[row][i]) * v);
                    } else {                          // w5: 1e x 1e -> 1e (cross)
                        int d = n - 1600; int i = d >> 3, j = d & 7;
                        float sv = 0.14433756729740643f * v;
                        atomicAdd(&s_out[row][32 + j * 3 + 0], sv * b2f(s_cr[row][i * 3 + 0]));
                        atomicAdd(&s_out[row][32 + j * 3 + 1], sv * b2f(s_cr[row][i * 3 + 1]));
                        atomicAdd(&s_out[row][32 + j * 3 + 2], sv * b2f(s_cr[row][i * 3 + 2]));
                    }
                }
            }
        }
    }
    __syncthreads();
    for (int i = t; i < 64 * 56; i += 256) {
        int eL = i / 56, d = i - 56 * (i / 56);
        float v = ((float*)s_out)[i] * s_ic[eL];
        int node = s_src[eL];
        if (d < 32) atomicAdd(&ags[node * CS + d], v);
        else        atomicAdd(&agv[node * 24 + (d - 32)], v);
    }
}

// ---------------------------------------------------------------------------
// Weight convert+transpose: src fp32 [L,R,C] -> dst bf16 [L,C,R]
// ---------------------------------------------------------------------------
__global__ void transpose_b(const float* __restrict__ src, bf16* __restrict__ dst,
                            int L, int R, int C)
{
    int idx = blockIdx.x * 256 + threadIdx.x;
    if (idx >= L * R * C) return;
    int l = idx / (R * C);
    int rem = idx - l * R * C;
    int r = rem / C;
    int c = rem - r * C;
    dst[(size_t)l * R * C + (size_t)c * R + r] = f2b(src[idx]);
}

__global__ __launch_bounds__(64)
void node_embed(const float* __restrict__ node_raw, const float* __restrict__ ne_ws,
                const float* __restrict__ ne_wv, float* __restrict__ xs, float* __restrict__ xv)
{
    int n = blockIdx.x, t = threadIdx.x;
    const float* nr = node_raw + (size_t)n * NRDIM;
    if (t < 32) {
        float acc = 0.f;
        for (int i = 0; i < INS; i++) acc += nr[i] * ne_ws[i * CS + t];
        xs[n * CS + t] = acc;
    } else if (t < 56) {
        int t2 = t - 32, j = t2 / 3, x = t2 - 3 * (t2 / 3);
        float acc = 0.f;
        for (int i = 0; i < INV; i++) acc += nr[INS + i * 3 + x] * ne_wv[i * CV + j];
        xv[n * 24 + t2] = acc;
    }
}

__global__ void count_src(const int* __restrict__ ei, int* __restrict__ cnt)
{
    int e = blockIdx.x * 256 + threadIdx.x;
    if (e < NE) atomicAdd(&cnt[ei[NE + e]], 1);
}

__global__ void make_icnt(const int* __restrict__ cnt, float* __restrict__ icnt)
{
    int n = blockIdx.x * 256 + threadIdx.x;
    if (n < NN) icnt[n] = 1.0f / (float)(cnt[n] > 1 ? cnt[n] : 1);
}

// LayerNorm over 128 dims, bf16 input; optional bf16 residual (may alias out).
template<int RESID>
__global__ __launch_bounds__(128)
void ln_kernel(const bf16* __restrict__ xin, const bf16* resid,
               const float* __restrict__ g, const float* __restrict__ b,
               bf16* efb)
{
    __shared__ float red[4];
    int r = blockIdx.x, t = threadIdx.x;
    float x = b2f(xin[(size_t)r * CZ + t]);
    if (RESID) x += b2f(resid[(size_t)r * CZ + t]);
    float s = x, s2 = x * x;
    for (int o = 32; o > 0; o >>= 1) { s += __shfl_down(s, o); s2 += __shfl_down(s2, o); }
    int w = t >> 6;
    if ((t & 63) == 0) { red[w * 2] = s; red[w * 2 + 1] = s2; }
    __syncthreads();
    float mean = (red[0] + red[2]) * (1.f / 128.f);
    float var  = (red[1] + red[3]) * (1.f / 128.f) - mean * mean;
    float rstd = rsqrtf(var + 1e-5f);
    float y = (x - mean) * rstd * g[t] + b[t];
    efb[(size_t)r * CZ + t] = f2b(y);
}

__global__ void add_agg(float* __restrict__ xs, float* __restrict__ xv,
                        const float* __restrict__ ags, const float* __restrict__ agv)
{
    int idx = blockIdx.x * 256 + threadIdx.x;
    if (idx >= NN * 56) return;
    int n = idx / 56, d = idx - 56 * (idx / 56);
    if (d < 32) xs[n * CS + d] += ags[n * CS + d];
    else        xv[n * 24 + d - 32] += agv[n * 24 + d - 32];
}

// blocks 0..31: xs channel mean/rstd -> stats[0..63]; 32..39: xv scale -> stats[64..71]
__global__ __launch_bounds__(256)
void bn_stats(const float* __restrict__ xs, const float* __restrict__ xv,
              const float* __restrict__ bn_vg_l, float* __restrict__ stats)
{
    __shared__ float red[8];
    int c = blockIdx.x, t = threadIdx.x;
    if (c < 32) {
        float s = 0.f, s2 = 0.f;
        for (int n = t; n < NN; n += 256) { float v = xs[n * CS + c]; s += v; s2 += v * v; }
        for (int o = 32; o > 0; o >>= 1) { s += __shfl_down(s, o); s2 += __shfl_down(s2, o); }
        int w = t >> 6;
        if ((t & 63) == 0) { red[w * 2] = s; red[w * 2 + 1] = s2; }
        __syncthreads();
        if (t == 0) {
            float S = red[0] + red[2] + red[4] + red[6];
            float S2 = red[1] + red[3] + red[5] + red[7];
            float mean = S * (1.f / NN);
            float var = S2 * (1.f / NN) - mean * mean;
            stats[c] = mean;
            stats[32 + c] = rsqrtf(var + 1e-5f);
        }
    } else {
        int c2 = c - 32;
        float s = 0.f;
        for (int n = t; n < NN; n += 256) {
            float v0 = xv[n * 24 + c2 * 3 + 0];
            float v1 = xv[n * 24 + c2 * 3 + 1];
            float v2 = xv[n * 24 + c2 * 3 + 2];
            s += v0 * v0 + v1 * v1 + v2 * v2;
        }
        for (int o = 32; o > 0; o >>= 1) s += __shfl_down(s, o);
        int w = t >> 6;
        if ((t & 63) == 0) red[w] = s;
        __syncthreads();
        if (t == 0) {
            float fn = (red[0] + red[1] + red[2] + red[3]) * (1.f / (3.f * NN));
            stats[64 + c2] = bn_vg_l[c2] * rsqrtf(fn + 1e-5f);
        }
    }
}

__global__ void bn_apply(float* __restrict__ xs, float* __restrict__ xv,
                         const float* __restrict__ stats,
                         const float* __restrict__ g, const float* __restrict__ b)
{
    int idx = blockIdx.x * 256 + threadIdx.x;
    if (idx >= NN * 56) return;
    int n = idx / 56, d = idx - 56 * (idx / 56);
    if (d < 32) {
        float v = xs[n * CS + d];
        xs[n * CS + d] = (v - stats[d]) * stats[32 + d] * g[d] + b[d];
    } else {
        int t2 = d - 32, c = t2 / 3;
        xv[n * 24 + t2] *= stats[64 + c];
    }
}

// a[n,128] = xs[n,:] @ eu_lin[l]
__global__ __launch_bounds__(128)
void lin_a(const float* __restrict__ xs, const float* __restrict__ eu_lin_l,
           bf16* __restrict__ a_b)
{
    __shared__ float sxs[32];
    int n = blockIdx.x, t = threadIdx.x;
    if (t < 32) sxs[t] = xs[n * CS + t];
    __syncthreads();
    float acc = 0.f;
    for (int c = 0; c < 32; c++) acc += sxs[c] * eu_lin_l[c * CZ + t];
    a_b[(size_t)n * CZ + t] = f2b(acc);
}

// Final: xv_loc = R^T v per node, feat=[xs|xv_loc] (56), mu/lv heads -> out [2,N,128] fp32
__global__ __launch_bounds__(128)
void final_out(const float* __restrict__ xs, const float* __restrict__ xv,
               const float* __restrict__ rot,
               const float* __restrict__ mu_w, const float* __restrict__ mu_b,
               const float* __restrict__ lv_w, const float* __restrict__ lv_b,
               float* __restrict__ out)
{
    __shared__ float feat[56];
    int n = blockIdx.x, t = threadIdx.x;
    if (t < 32) feat[t] = xs[n * CS + t];
    else if (t < 56) {
        int t2 = t - 32, c = t2 / 3, y = t2 - 3 * (t2 / 3);
        float acc = 0.f;
        for (int x = 0; x < 3; x++)
            acc += rot[n * 9 + x * 3 + y] * xv[n * 24 + c * 3 + x];
        feat[t] = acc;
    }
    __syncthreads();
    float mu = mu_b[t], lv = lv_b[t];
    for (int d = 0; d < 56; d++) {
        float f = feat[d];
        mu += f * mu_w[d * 128 + t];
        lv += f * lv_w[d * 128 + t];
    }
    out[(size_t)n * 128 + t] = mu;
    out[(size_t)NN * 128 + (size_t)n * 128 + t] = lv;
}

// ---------------------------------------------------------------------------
extern "C" void kernel_launch(void* const* d_in, const int* in_sizes, int n_in,
                              void* d_out, int out_size, void* d_ws, size_t ws_size,
                              hipStream_t stream)
{
    (void)in_sizes; (void)n_in; (void)out_size; (void)ws_size;
    const float* node_raw  = (const float*)d_in[0];
    const float* edge_raw  = (const float*)d_in[1];
    const float* edge_vecs = (const float*)d_in[2];
    const float* rot       = (const float*)d_in[3];
    const int*   ei        = (const int*  )d_in[4];
    const float* ee_w1 = (const float*)d_in[5];
    const float* ee_b1 = (const float*)d_in[6];
    const float* ee_w2 = (const float*)d_in[7];
    const float* ee_b2 = (const float*)d_in[8];
    const float* ee_w3 = (const float*)d_in[9];
    const float* ee_b3 = (const float*)d_in[10];
    const float* ee_ln_g = (const float*)d_in[11];
    const float* ee_ln_b = (const float*)d_in[12];
    const float* ne_ws = (const float*)d_in[13];
    const float* ne_wv = (const float*)d_in[14];
    const float* fc_w1 = (const float*)d_in[15];
    const float* fc_b1 = (const float*)d_in[16];
    const float* fc_w2 = (const float*)d_in[17];
    const float* fc_b2 = (const float*)d_in[18];
    const float* bn_g  = (const float*)d_in[19];
    const float* bn_b  = (const float*)d_in[20];
    const float* bn_vg = (const float*)d_in[21];
    const float* eu_lin = (const float*)d_in[22];
    const float* eu_w1 = (const float*)d_in[23];
    const float* eu_b1 = (const float*)d_in[24];
    const float* eu_w2 = (const float*)d_in[25];
    const float* eu_b2 = (const float*)d_in[26];
    const float* eu_w3 = (const float*)d_in[27];
    const float* eu_b3 = (const float*)d_in[28];
    const float* eu_ln_g = (const float*)d_in[29];
    const float* eu_ln_b = (const float*)d_in[30];
    const float* mu_w = (const float*)d_in[31];
    const float* mu_b = (const float*)d_in[32];
    const float* lv_w = (const float*)d_in[33];
    const float* lv_b = (const float*)d_in[34];

    char* ws = (char*)d_ws;
    size_t off = 0;
    auto alloc = [&](size_t bytes) -> void* {
        void* p = ws + off;
        off += (bytes + 255) & ~(size_t)255;
        return p;
    };
    // total footprint ~28 MB
    bf16*  ef_b  = (bf16*) alloc((size_t)NE * CZ * 2);     // residual stream
    bf16*  buf_a = (bf16*) alloc((size_t)NE * CZ * 2);
    bf16*  buf_b = (bf16*) alloc((size_t)NE * CZ * 2);
    float* xs    = (float*)alloc((size_t)NN * CS * 4);
    float* xv    = (float*)alloc((size_t)NN * 24 * 4);
    float* ags   = (float*)alloc((size_t)NN * CS * 4);
    float* agv   = (float*)alloc((size_t)NN * 24 * 4);
    int*   cnti  = (int*)  alloc((size_t)NN * 4);
    float* icnt  = (float*)alloc((size_t)NN * 4);
    float* stats = (float*)alloc(256 * 4);
    bf16*  a_b   = (bf16*) alloc((size_t)NN * CZ * 2);
    bf16* ee_w1t = (bf16*)alloc((size_t)INZ * CZ * 2);
    bf16* ee_w2t = (bf16*)alloc((size_t)CZ * CZ * 2);
    bf16* ee_w3t = (bf16*)alloc((size_t)CZ * CZ * 2);
    bf16* fc_w1t = (bf16*)alloc((size_t)NL * CZ * CZ * 2);
    bf16* fc_w2t = (bf16*)alloc((size_t)NL * WN * CZ * 2);
    bf16* eu_w1t = (bf16*)alloc((size_t)NL * 384 * CZ * 2);
    bf16* eu_w2t = (bf16*)alloc((size_t)NL * CZ * CZ * 2);
    bf16* eu_w3t = (bf16*)alloc((size_t)NL * CZ * CZ * 2);

    auto tg = [](int n) { return (n + 255) / 256; };
    transpose_b<<<tg(INZ * CZ), 256, 0, stream>>>(ee_w1, ee_w1t, 1, INZ, CZ);
    transpose_b<<<tg(CZ * CZ), 256, 0, stream>>>(ee_w2, ee_w2t, 1, CZ, CZ);
    transpose_b<<<tg(CZ * CZ), 256, 0, stream>>>(ee_w3, ee_w3t, 1, CZ, CZ);
    transpose_b<<<tg(NL * CZ * CZ), 256, 0, stream>>>(fc_w1, fc_w1t, NL, CZ, CZ);
    transpose_b<<<tg(NL * CZ * WN), 256, 0, stream>>>(fc_w2, fc_w2t, NL, CZ, WN);
    transpose_b<<<tg(NL * 384 * CZ), 256, 0, stream>>>(eu_w1, eu_w1t, NL, 384, CZ);
    transpose_b<<<tg(NL * CZ * CZ), 256, 0, stream>>>(eu_w2, eu_w2t, NL, CZ, CZ);
    transpose_b<<<tg(NL * CZ * CZ), 256, 0, stream>>>(eu_w3, eu_w3t, NL, CZ, CZ);

    node_embed<<<NN, 64, 0, stream>>>(node_raw, ne_ws, ne_wv, xs, xv);
    hipMemsetAsync(cnti, 0, NN * 4, stream);
    count_src<<<NE / 256, 256, 0, stream>>>(ei, cnti);
    make_icnt<<<NN / 256, 256, 0, stream>>>(cnti, icnt);

    const int GE = NE / 64;   // 480 blocks for edge-tensor GEMMs
    // edge embedding MLP + LN  (edge_raw(fp32) -> buf_a -> buf_b -> buf_a -> ef_b)
    gemm64<1, 1, 0><<<GE, 256, 0, stream>>>(edge_raw, ee_w1t, ee_b1, buf_a, NE, INZ, nullptr, nullptr, nullptr);
    gemm64<1, 0, 0><<<GE, 256, 0, stream>>>(buf_a, ee_w2t, ee_b2, buf_b, NE, CZ, nullptr, nullptr, nullptr);
    gemm64<0, 0, 0><<<GE, 256, 0, stream>>>(buf_b, ee_w3t, ee_b3, buf_a, NE, CZ, nullptr, nullptr, nullptr);
    ln_kernel<0><<<NE, 128, 0, stream>>>(buf_a, nullptr, ee_ln_g, ee_ln_b, ef_b);

    for (int l = 0; l < NL; l++) {
        gemm64<1, 0, 0><<<GE, 256, 0, stream>>>(
            ef_b, fc_w1t + (size_t)l * CZ * CZ, fc_b1 + l * CZ, buf_a, NE, CZ, nullptr, nullptr, nullptr);
        hipMemsetAsync(ags, 0, NN * CS * 4, stream);
        hipMemsetAsync(agv, 0, NN * 24 * 4, stream);
        fc2_tp<<<GE, 256, 0, stream>>>(
            buf_a, fc_w2t + (size_t)l * WN * CZ, fc_b2 + l * WN, ei, edge_vecs,
            xs, xv, icnt, ags, agv);
        add_agg<<<(NN * 56) / 256, 256, 0, stream>>>(xs, xv, ags, agv);
        bn_stats<<<40, 256, 0, stream>>>(xs, xv, bn_vg + l * CV, stats);
        bn_apply<<<(NN * 56) / 256, 256, 0, stream>>>(xs, xv, stats, bn_g + l * CS, bn_b + l * CS);
        lin_a<<<NN, 128, 0, stream>>>(xs, eu_lin + (size_t)l * CS * CZ, a_b);
        gemm64<1, 0, 1><<<GE, 256, 0, stream>>>(
            nullptr, eu_w1t + (size_t)l * 384 * CZ, eu_b1 + l * CZ, buf_a, NE, 384, a_b, ef_b, ei);
        gemm64<1, 0, 0><<<GE, 256, 0, stream>>>(
            buf_a, eu_w2t + (size_t)l * CZ * CZ, eu_b2 + l * CZ, buf_b, NE, CZ, nullptr, nullptr, nullptr);
        gemm64<0, 0, 0><<<GE, 256, 0, stream>>>(
            buf_b, eu_w3t + (size_t)l * CZ * CZ, eu_b3 + l * CZ, buf_a, NE, CZ, nullptr, nullptr, nullptr);
        ln_kernel<1><<<NE, 128, 0, stream>>>(buf_a, ef_b, eu_ln_g + l * CZ, eu_ln_b + l * CZ, ef_b);
    }

    final_out<<<NN, 128, 0, stream>>>(xs, xv, rot, mu_w, mu_b, lv_w, lv_b, (float*)d_out);
}

// Round 5
// 1103.104 us; speedup vs baseline: 2.1202x; 2.1202x over previous
//
#include <hip/hip_runtime.h>
#include <hip/hip_bf16.h>

typedef __hip_bfloat16 bf16;
typedef __attribute__((ext_vector_type(8))) short s16x8;   // 8 bf16 (4 VGPRs) MFMA frag
typedef __attribute__((ext_vector_type(4))) float f32x4;   // MFMA accumulator

#define NN 1024      // nodes
#define NE 30720     // edges
#define CS 32
#define CV 8
#define CZ 128
#define INS 28
#define INV 37
#define NRDIM 139    // 28 + 3*37
#define INZ 1664
#define WN 1664      // WEIGHT_NUMEL
#define NL 4

__device__ __forceinline__ float b2f(bf16 x) { return __bfloat162float(x); }
__device__ __forceinline__ bf16 f2b(float x) { return __float2bfloat16(x); }

// ---------------------------------------------------------------------------
// Skinny MFMA GEMM, N=128 fixed (used for ee1 K=1664 fp32-A and eu1 gather).
// Tile M=64 -> grid 480. AF32: A fp32 converted in staging. GATHER: row e =
// [a_b[dst[e]] | a_b[src[e]] | ef_b[e]] (K=384).
// ---------------------------------------------------------------------------
template<int RELU, int AF32, int GATHER>
__global__ __launch_bounds__(256)
void gemm64(const void* __restrict__ Ap, const bf16* __restrict__ Bt,
            const float* __restrict__ bias, bf16* __restrict__ Cp,
            int M, int K,
            const bf16* __restrict__ g_a, const bf16* __restrict__ g_ef,
            const int* __restrict__ g_ei)
{
    __shared__ __align__(16) bf16 la[64 * 40];
    __shared__ __align__(16) bf16 lb[128 * 40];
    const int bm = blockIdx.x * 64;
    const int tid = threadIdx.x;
    const int lane = tid & 63;
    const int wv = tid >> 6;
    const int lr = tid >> 1;
    const int lc = (tid & 1) * 16;
    const int l15 = lane & 15;
    const int quad = lane >> 4;
    f32x4 acc[4][2] = {};
    const bf16* gb = Bt + (size_t)lr * K + lc;
    const bf16*  ga16 = (const bf16*) Ap + (size_t)(bm + lr) * K + lc;
    const float* ga32 = (const float*)Ap + (size_t)(bm + lr) * K + lc;
    int gdst = 0, gsrc = 0, grow = 0;
    if (GATHER && tid < 128) {
        grow = bm + lr;
        gdst = g_ei[grow];
        gsrc = g_ei[NE + grow];
    }
    for (int k0 = 0; k0 < K; k0 += 32) {
        union { bf16 h[16]; float4 q[2]; } pa;
        if (tid < 128) {
            if (AF32) {
                float4 f0 = *(const float4*)(ga32 + k0);
                float4 f1 = *(const float4*)(ga32 + k0 + 4);
                float4 f2 = *(const float4*)(ga32 + k0 + 8);
                float4 f3 = *(const float4*)(ga32 + k0 + 12);
                pa.h[0]=f2b(f0.x); pa.h[1]=f2b(f0.y); pa.h[2]=f2b(f0.z); pa.h[3]=f2b(f0.w);
                pa.h[4]=f2b(f1.x); pa.h[5]=f2b(f1.y); pa.h[6]=f2b(f1.z); pa.h[7]=f2b(f1.w);
                pa.h[8]=f2b(f2.x); pa.h[9]=f2b(f2.y); pa.h[10]=f2b(f2.z); pa.h[11]=f2b(f2.w);
                pa.h[12]=f2b(f3.x); pa.h[13]=f2b(f3.y); pa.h[14]=f2b(f3.z); pa.h[15]=f2b(f3.w);
            } else if (GATHER) {
                int kk = k0 + lc;
                const bf16* src;
                if (kk < 128)      src = g_a  + (size_t)gdst * CZ + kk;
                else if (kk < 256) src = g_a  + (size_t)gsrc * CZ + (kk - 128);
                else               src = g_ef + (size_t)grow * CZ + (kk - 256);
                pa.q[0] = *(const float4*)src;
                pa.q[1] = *(const float4*)(src + 8);
            } else {
                pa.q[0] = *(const float4*)(ga16 + k0);
                pa.q[1] = *(const float4*)(ga16 + k0 + 8);
            }
        }
        float4 b0 = *(const float4*)(gb + k0);
        float4 b1 = *(const float4*)(gb + k0 + 8);
        __syncthreads();
        if (tid < 128) {
            *(float4*)&la[lr * 40 + lc]     = pa.q[0];
            *(float4*)&la[lr * 40 + lc + 8] = pa.q[1];
        }
        *(float4*)&lb[lr * 40 + lc]     = b0;
        *(float4*)&lb[lr * 40 + lc + 8] = b1;
        __syncthreads();
        s16x8 af[4], bfr[2];
#pragma unroll
        for (int mi = 0; mi < 4; mi++)
            af[mi] = *(const s16x8*)&la[(mi * 16 + l15) * 40 + quad * 8];
#pragma unroll
        for (int ni = 0; ni < 2; ni++)
            bfr[ni] = *(const s16x8*)&lb[(wv * 32 + ni * 16 + l15) * 40 + quad * 8];
#pragma unroll
        for (int mi = 0; mi < 4; mi++)
#pragma unroll
            for (int ni = 0; ni < 2; ni++)
                acc[mi][ni] = __builtin_amdgcn_mfma_f32_16x16x32_bf16(af[mi], bfr[ni], acc[mi][ni], 0, 0, 0);
    }
#pragma unroll
    for (int ni = 0; ni < 2; ni++) {
        const int col = wv * 32 + ni * 16 + l15;
        const float bv = bias[col];
#pragma unroll
        for (int mi = 0; mi < 4; mi++) {
            const int row0 = bm + mi * 16 + quad * 4;
#pragma unroll
            for (int r = 0; r < 4; r++) {
                float v = acc[mi][ni][r] + bv;
                if (RELU) v = fmaxf(v, 0.f);
                Cp[(size_t)(row0 + r) * CZ + col] = f2b(v);
            }
        }
    }
}

// ---------------------------------------------------------------------------
// Fused MLP tail: u2 = relu(A@W2+b2); u3 = u2@W3+b3 (+resid); LN -> efb (bf16)
// Block = 64 rows. Used for ee (RESID=0) and eu (RESID=1, resid==efb in/out).
// W matrices streamed per-lane from global (L2-resident, 32 KB each).
// ---------------------------------------------------------------------------
template<int RESID>
__global__ __launch_bounds__(256)
void mlp2(const bf16* __restrict__ A,
          const bf16* __restrict__ w2t, const float* __restrict__ b2,
          const bf16* __restrict__ w3t, const float* __restrict__ b3,
          const float* __restrict__ g, const float* __restrict__ bb,
          bf16* efb)
{
    __shared__ __align__(16) bf16 s_a[64 * 136];
    __shared__ __align__(16) bf16 s_u[64 * 136];
    __shared__ float s_o[64 * 132];
    const int bm = blockIdx.x * 64;
    const int t = threadIdx.x;
    const int lane = t & 63;
    const int wv = t >> 6;
    const int l15 = lane & 15;
    const int quad = lane >> 4;
    {   // stage A tile 64x128
        int r = t >> 2, c0 = (t & 3) * 32;
        const float4* s4 = (const float4*)(A + (size_t)(bm + r) * CZ + c0);
        float4* d4 = (float4*)&s_a[r * 136 + c0];
        d4[0] = s4[0]; d4[1] = s4[1]; d4[2] = s4[2]; d4[3] = s4[3];
    }
    __syncthreads();
    s16x8 af[4][4];
#pragma unroll
    for (int mi = 0; mi < 4; mi++)
#pragma unroll
        for (int kk = 0; kk < 4; kk++)
            af[mi][kk] = *(const s16x8*)&s_a[(mi * 16 + l15) * 136 + kk * 32 + quad * 8];
    // stage 1: relu(A@W2+b2) -> s_u
#pragma unroll
    for (int s = 0; s < 2; s++) {
        int n = wv * 32 + s * 16 + l15;
        f32x4 acc[4] = {};
#pragma unroll
        for (int kk = 0; kk < 4; kk++) {
            s16x8 bfr = *(const s16x8*)(w2t + (size_t)n * CZ + kk * 32 + quad * 8);
#pragma unroll
            for (int mi = 0; mi < 4; mi++)
                acc[mi] = __builtin_amdgcn_mfma_f32_16x16x32_bf16(af[mi][kk], bfr, acc[mi], 0, 0, 0);
        }
        float bv = b2[n];
#pragma unroll
        for (int mi = 0; mi < 4; mi++)
#pragma unroll
            for (int r = 0; r < 4; r++)
                s_u[(mi * 16 + quad * 4 + r) * 136 + n] = f2b(fmaxf(acc[mi][r] + bv, 0.f));
    }
    __syncthreads();
#pragma unroll
    for (int mi = 0; mi < 4; mi++)
#pragma unroll
        for (int kk = 0; kk < 4; kk++)
            af[mi][kk] = *(const s16x8*)&s_u[(mi * 16 + l15) * 136 + kk * 32 + quad * 8];
    // stage 2: u2@W3+b3 -> s_o (f32)
#pragma unroll
    for (int s = 0; s < 2; s++) {
        int n = wv * 32 + s * 16 + l15;
        f32x4 acc[4] = {};
#pragma unroll
        for (int kk = 0; kk < 4; kk++) {
            s16x8 bfr = *(const s16x8*)(w3t + (size_t)n * CZ + kk * 32 + quad * 8);
#pragma unroll
            for (int mi = 0; mi < 4; mi++)
                acc[mi] = __builtin_amdgcn_mfma_f32_16x16x32_bf16(af[mi][kk], bfr, acc[mi], 0, 0, 0);
        }
        float bv = b3[n];
#pragma unroll
        for (int mi = 0; mi < 4; mi++)
#pragma unroll
            for (int r = 0; r < 4; r++)
                s_o[(mi * 16 + quad * 4 + r) * 132 + n] = acc[mi][r] + bv;
    }
    __syncthreads();
    // LN per row: 4 lanes per row, 32 cols each
    {
        int row = wv * 16 + (lane >> 2);
        int q = lane & 3;
        int col0 = q * 32;
        size_t gbase = (size_t)(bm + row) * CZ;
        float s = 0.f, s2 = 0.f;
        for (int i = 0; i < 32; i++) {
            float x = s_o[row * 132 + col0 + i];
            if (RESID) x += b2f(efb[gbase + col0 + i]);
            s += x; s2 += x * x;
        }
        s  += __shfl_xor(s, 1);  s2 += __shfl_xor(s2, 1);
        s  += __shfl_xor(s, 2);  s2 += __shfl_xor(s2, 2);
        float mean = s * (1.f / 128.f);
        float var  = s2 * (1.f / 128.f) - mean * mean;
        float rstd = rsqrtf(var + 1e-5f);
        for (int i = 0; i < 32; i++) {
            int col = col0 + i;
            float x = s_o[row * 132 + col];
            if (RESID) x += b2f(efb[gbase + col]);
            efb[gbase + col] = f2b((x - mean) * rstd * g[col] + bb[col]);
        }
    }
}

// ---------------------------------------------------------------------------
// Fused fc1 + fc2 + tensor product + scatter.  Block = 16 edges (grid 1920).
// h = relu(ef@W1+b1) [16x128] in LDS -> w = h@W2+b2 [16x1664] bf16 in LDS
// (s_wT[n][e], never touches global) -> TP: each thread owns one (edge,out-dim),
// register accumulation, ONE global atomic per output. No LDS atomics.
// ---------------------------------------------------------------------------
__global__ __launch_bounds__(256)
void fc2_tp(const bf16* __restrict__ ef,
            const bf16* __restrict__ w1t, const float* __restrict__ b1,
            const bf16* __restrict__ w2t, const float* __restrict__ b2,
            const int* __restrict__ ei, const float* __restrict__ edge_vecs,
            const float* __restrict__ xs, const float* __restrict__ xv,
            const float* __restrict__ icnt,
            float* __restrict__ ags, float* __restrict__ agv)
{
    __shared__ __align__(16) bf16 s_wT[WN * 16];     // 53.2 KB  w[n][e]
    __shared__ __align__(16) bf16 s_a[16 * 136];
    __shared__ __align__(16) bf16 s_h[16 * 136];
    __shared__ float s_xs[16][33];
    __shared__ float s_xv[16][25];
    __shared__ float s_cr[16][25];
    __shared__ float s_y4[16][9];
    __shared__ float s_shv[16][3];
    __shared__ float s_ic[16];
    __shared__ int s_dst[16], s_src[16];
    const int be = blockIdx.x * 16;
    const int t = threadIdx.x;
    const int lane = t & 63;
    const int wv = t >> 6;
    const int l15 = lane & 15;
    const int quad = lane >> 4;

    if (t < 16) {
        int e = be + t;
        int d = ei[e], s = ei[NE + e];
        s_dst[t] = d; s_src[t] = s; s_ic[t] = icnt[s];
        float vx = edge_vecs[e * 3 + 0];
        float vy = edge_vecs[e * 3 + 1];
        float vz = edge_vecs[e * 3 + 2];
        float sc = 1.7320508075688772f / (sqrtf(vx * vx + vy * vy + vz * vz) + 1e-8f);
        s_shv[t][0] = vx * sc; s_shv[t][1] = vy * sc; s_shv[t][2] = vz * sc;
    }
    __syncthreads();
    for (int i = t; i < 16 * 32; i += 256) { int e = i >> 5, c = i & 31; s_xs[e][c] = xs[s_dst[e] * CS + c]; }
    for (int i = t; i < 16 * 24; i += 256) { int e = i / 24, c = i - 24 * e; s_xv[e][c] = xv[s_dst[e] * 24 + c]; }
    {   // stage ef tile 16x128
        int r = t >> 4, c0 = (t & 15) * 8;
        *(float4*)&s_a[r * 136 + c0] = *(const float4*)(ef + (size_t)(be + r) * CZ + c0);
    }
    __syncthreads();
    if (t < 128) {   // y4 + cross
        int e = t >> 3, i = t & 7;
        float h0 = s_shv[e][0], h1 = s_shv[e][1], h2 = s_shv[e][2];
        float x0 = s_xv[e][i * 3 + 0], x1 = s_xv[e][i * 3 + 1], x2 = s_xv[e][i * 3 + 2];
        s_y4[e][i] = x0 * h0 + x1 * h1 + x2 * h2;
        s_cr[e][i * 3 + 0] = x1 * h2 - x2 * h1;
        s_cr[e][i * 3 + 1] = x2 * h0 - x0 * h2;
        s_cr[e][i * 3 + 2] = x0 * h1 - x1 * h0;
    }
    // phase 1: h = relu(ef@W1+b1), M=16 N=128 K=128
    s16x8 af1[4];
#pragma unroll
    for (int kk = 0; kk < 4; kk++)
        af1[kk] = *(const s16x8*)&s_a[l15 * 136 + kk * 32 + quad * 8];
#pragma unroll
    for (int s = 0; s < 2; s++) {
        int n = wv * 32 + s * 16 + l15;
        f32x4 acc = {};
#pragma unroll
        for (int kk = 0; kk < 4; kk++) {
            s16x8 bfr = *(const s16x8*)(w1t + (size_t)n * CZ + kk * 32 + quad * 8);
            acc = __builtin_amdgcn_mfma_f32_16x16x32_bf16(af1[kk], bfr, acc, 0, 0, 0);
        }
        float bv = b1[n];
#pragma unroll
        for (int r = 0; r < 4; r++)
            s_h[(quad * 4 + r) * 136 + n] = f2b(fmaxf(acc[r] + bv, 0.f));
    }
    __syncthreads();
    // phase 2: w = h@W2+b2 -> s_wT[n][e]
    s16x8 af[4];
#pragma unroll
    for (int kk = 0; kk < 4; kk++)
        af[kk] = *(const s16x8*)&s_h[l15 * 136 + kk * 32 + quad * 8];
    for (int nt = wv; nt < 104; nt += 4) {
        int n = nt * 16 + l15;
        f32x4 acc = {};
#pragma unroll
        for (int kk = 0; kk < 4; kk++) {
            s16x8 bfr = *(const s16x8*)(w2t + (size_t)n * CZ + kk * 32 + quad * 8);
            acc = __builtin_amdgcn_mfma_f32_16x16x32_bf16(af[kk], bfr, acc, 0, 0, 0);
        }
        float bv = b2[n];
        union { bf16 h[4]; uint2 u; } pk;
#pragma unroll
        for (int r = 0; r < 4; r++) pk.h[r] = f2b(acc[r] + bv);
        *(uint2*)&s_wT[n * 16 + quad * 4] = pk.u;   // 8B, edges quad*4..+3
    }
    __syncthreads();
    // phase 3: TP, thread owns (e, d)
    {
        int e = t & 15, slot = t >> 4;
        float ic = s_ic[e];
        int src = s_src[e];
        for (int d = slot; d < 56; d += 16) {
            if (d < 32) {
                float a1 = 0.f, a4 = 0.f;
                for (int i = 0; i < 32; i++) a1 += s_xs[e][i] * b2f(s_wT[(i * 32 + d) * 16 + e]);
                for (int i = 0; i < 8; i++)  a4 += s_y4[e][i] * b2f(s_wT[(1344 + i * 32 + d) * 16 + e]);
                atomicAdd(&ags[src * CS + d], (0.125f * a1 + 0.14433756729740643f * a4) * ic);
            } else {
                int dd = d - 32;
                int j = (dd * 11) >> 5;
                int x = dd - 3 * j;
                float a2 = 0.f, a3 = 0.f, a5 = 0.f;
                for (int i = 0; i < 32; i++) a2 += s_xs[e][i] * b2f(s_wT[(1024 + i * 8 + j) * 16 + e]);
                for (int i = 0; i < 8; i++) {
                    a3 += s_xv[e][i * 3 + x] * b2f(s_wT[(1280 + i * 8 + j) * 16 + e]);
                    a5 += s_cr[e][i * 3 + x] * b2f(s_wT[(1600 + i * 8 + j) * 16 + e]);
                }
                float out = 0.10206207261596575f * s_shv[e][x] * a2
                          + 0.2041241452319315f * a3
                          + 0.14433756729740643f * a5;
                atomicAdd(&agv[src * 24 + dd], out * ic);
            }
        }
    }
}

// ---------------------------------------------------------------------------
__device__ __forceinline__ void trseg(int i, int R, int C,
                                      const float* __restrict__ s, bf16* __restrict__ d)
{
    int l = i / (R * C);
    int rem = i - l * R * C;
    int r = rem / C;
    int c = rem - r * C;
    d[(size_t)l * R * C + (size_t)c * R + r] = f2b(s[i]);
}

__global__ void transpose_all(const float* __restrict__ p0, const float* __restrict__ p1,
                              const float* __restrict__ p2, const float* __restrict__ p3,
                              const float* __restrict__ p4, const float* __restrict__ p5,
                              const float* __restrict__ p6, const float* __restrict__ p7,
                              bf16* d0, bf16* d1, bf16* d2, bf16* d3,
                              bf16* d4, bf16* d5, bf16* d6, bf16* d7)
{
    int i = blockIdx.x * 256 + threadIdx.x;
    const int S0 = INZ * CZ;            // ee_w1  212992
    const int S1 = CZ * CZ;             // ee_w2
    const int S2 = CZ * CZ;             // ee_w3
    const int S3 = NL * CZ * CZ;        // fc_w1
    const int S4 = NL * CZ * WN;        // fc_w2  851968
    const int S5 = NL * 384 * CZ;       // eu_w1
    const int S6 = NL * CZ * CZ;        // eu_w2
    const int S7 = NL * CZ * CZ;        // eu_w3
    if (i < S0) { trseg(i, INZ, CZ, p0, d0); return; } i -= S0;
    if (i < S1) { trseg(i, CZ, CZ, p1, d1); return; }  i -= S1;
    if (i < S2) { trseg(i, CZ, CZ, p2, d2); return; }  i -= S2;
    if (i < S3) { trseg(i, CZ, CZ, p3, d3); return; }  i -= S3;
    if (i < S4) { trseg(i, CZ, WN, p4, d4); return; }  i -= S4;
    if (i < S5) { trseg(i, 384, CZ, p5, d5); return; } i -= S5;
    if (i < S6) { trseg(i, CZ, CZ, p6, d6); return; }  i -= S6;
    if (i < S7) { trseg(i, CZ, CZ, p7, d7); return; }
}

__global__ __launch_bounds__(64)
void node_embed(const float* __restrict__ node_raw, const float* __restrict__ ne_ws,
                const float* __restrict__ ne_wv, float* __restrict__ xs, float* __restrict__ xv)
{
    int n = blockIdx.x, t = threadIdx.x;
    const float* nr = node_raw + (size_t)n * NRDIM;
    if (t < 32) {
        float acc = 0.f;
        for (int i = 0; i < INS; i++) acc += nr[i] * ne_ws[i * CS + t];
        xs[n * CS + t] = acc;
    } else if (t < 56) {
        int t2 = t - 32, j = t2 / 3, x = t2 - 3 * (t2 / 3);
        float acc = 0.f;
        for (int i = 0; i < INV; i++) acc += nr[INS + i * 3 + x] * ne_wv[i * CV + j];
        xv[n * 24 + t2] = acc;
    }
}

__global__ void count_src(const int* __restrict__ ei, int* __restrict__ cnt)
{
    int e = blockIdx.x * 256 + threadIdx.x;
    if (e < NE) atomicAdd(&cnt[ei[NE + e]], 1);
}

// icnt + zero ags/agv (covers idx < NN*32; agv is NN*24 < that)
__global__ void init_misc(const int* __restrict__ cnt, float* __restrict__ icnt,
                          float* __restrict__ ags, float* __restrict__ agv)
{
    int i = blockIdx.x * 256 + threadIdx.x;
    if (i < NN) icnt[i] = 1.0f / (float)(cnt[i] > 1 ? cnt[i] : 1);
    if (i < NN * CS) ags[i] = 0.f;
    if (i < NN * 24) agv[i] = 0.f;
}

// add agg + batchnorm stats + apply + zero agg for next layer.  40 blocks.
__global__ __launch_bounds__(256)
void bnfused(float* __restrict__ xs, float* __restrict__ xv,
             float* __restrict__ ags, float* __restrict__ agv,
             const float* __restrict__ g, const float* __restrict__ b,
             const float* __restrict__ vg)
{
    __shared__ float red[8];
    __shared__ float stat[2];
    int c = blockIdx.x, t = threadIdx.x;
    if (c < 32) {
        float s = 0.f, s2 = 0.f;
        for (int n = t; n < NN; n += 256) {
            float v = xs[n * CS + c] + ags[n * CS + c];
            s += v; s2 += v * v;
        }
        for (int o = 32; o > 0; o >>= 1) { s += __shfl_down(s, o); s2 += __shfl_down(s2, o); }
        int w = t >> 6;
        if ((t & 63) == 0) { red[w * 2] = s; red[w * 2 + 1] = s2; }
        __syncthreads();
        if (t == 0) {
            float S = red[0] + red[2] + red[4] + red[6];
            float S2 = red[1] + red[3] + red[5] + red[7];
            float mean = S * (1.f / NN);
            float var = S2 * (1.f / NN) - mean * mean;
            stat[0] = mean;
            stat[1] = rsqrtf(var + 1e-5f);
        }
        __syncthreads();
        float mean = stat[0], rstd = stat[1], gg = g[c], bb = b[c];
        for (int n = t; n < NN; n += 256) {
            int ix = n * CS + c;
            float v = xs[ix] + ags[ix];
            xs[ix] = (v - mean) * rstd * gg + bb;
            ags[ix] = 0.f;
        }
    } else {
        int c2 = c - 32;
        float s = 0.f;
        for (int n = t; n < NN; n += 256) {
            float v0 = xv[n * 24 + c2 * 3 + 0] + agv[n * 24 + c2 * 3 + 0];
            float v1 = xv[n * 24 + c2 * 3 + 1] + agv[n * 24 + c2 * 3 + 1];
            float v2 = xv[n * 24 + c2 * 3 + 2] + agv[n * 24 + c2 * 3 + 2];
            s += v0 * v0 + v1 * v1 + v2 * v2;
        }
        for (int o = 32; o > 0; o >>= 1) s += __shfl_down(s, o);
        int w = t >> 6;
        if ((t & 63) == 0) red[w] = s;
        __syncthreads();
        if (t == 0) {
            float fn = (red[0] + red[1] + red[2] + red[3]) * (1.f / (3.f * NN));
            stat[0] = vg[c2] * rsqrtf(fn + 1e-5f);
        }
        __syncthreads();
        float scale = stat[0];
        for (int n = t; n < NN; n += 256) {
            for (int x = 0; x < 3; x++) {
                int ix = n * 24 + c2 * 3 + x;
                float v = xv[ix] + agv[ix];
                xv[ix] = v * scale;
                agv[ix] = 0.f;
            }
        }
    }
}

// a[n,128] = xs[n,:] @ eu_lin[l]
__global__ __launch_bounds__(128)
void lin_a(const float* __restrict__ xs, const float* __restrict__ eu_lin_l,
           bf16* __restrict__ a_b)
{
    __shared__ float sxs[32];
    int n = blockIdx.x, t = threadIdx.x;
    if (t < 32) sxs[t] = xs[n * CS + t];
    __syncthreads();
    float acc = 0.f;
    for (int c = 0; c < 32; c++) acc += sxs[c] * eu_lin_l[c * CZ + t];
    a_b[(size_t)n * CZ + t] = f2b(acc);
}

__global__ __launch_bounds__(128)
void final_out(const float* __restrict__ xs, const float* __restrict__ xv,
               const float* __restrict__ rot,
               const float* __restrict__ mu_w, const float* __restrict__ mu_b,
               const float* __restrict__ lv_w, const float* __restrict__ lv_b,
               float* __restrict__ out)
{
    __shared__ float feat[56];
    int n = blockIdx.x, t = threadIdx.x;
    if (t < 32) feat[t] = xs[n * CS + t];
    else if (t < 56) {
        int t2 = t - 32, c = t2 / 3, y = t2 - 3 * (t2 / 3);
        float acc = 0.f;
        for (int x = 0; x < 3; x++)
            acc += rot[n * 9 + x * 3 + y] * xv[n * 24 + c * 3 + x];
        feat[t] = acc;
    }
    __syncthreads();
    float mu = mu_b[t], lv = lv_b[t];
    for (int d = 0; d < 56; d++) {
        float f = feat[d];
        mu += f * mu_w[d * 128 + t];
        lv += f * lv_w[d * 128 + t];
    }
    out[(size_t)n * 128 + t] = mu;
    out[(size_t)NN * 128 + (size_t)n * 128 + t] = lv;
}

// ---------------------------------------------------------------------------
extern "C" void kernel_launch(void* const* d_in, const int* in_sizes, int n_in,
                              void* d_out, int out_size, void* d_ws, size_t ws_size,
                              hipStream_t stream)
{
    (void)in_sizes; (void)n_in; (void)out_size; (void)ws_size;
    const float* node_raw  = (const float*)d_in[0];
    const float* edge_raw  = (const float*)d_in[1];
    const float* edge_vecs = (const float*)d_in[2];
    const float* rot       = (const float*)d_in[3];
    const int*   ei        = (const int*  )d_in[4];
    const float* ee_w1 = (const float*)d_in[5];
    const float* ee_b1 = (const float*)d_in[6];
    const float* ee_w2 = (const float*)d_in[7];
    const float* ee_b2 = (const float*)d_in[8];
    const float* ee_w3 = (const float*)d_in[9];
    const float* ee_b3 = (const float*)d_in[10];
    const float* ee_ln_g = (const float*)d_in[11];
    const float* ee_ln_b = (const float*)d_in[12];
    const float* ne_ws = (const float*)d_in[13];
    const float* ne_wv = (const float*)d_in[14];
    const float* fc_w1 = (const float*)d_in[15];
    const float* fc_b1 = (const float*)d_in[16];
    const float* fc_w2 = (const float*)d_in[17];
    const float* fc_b2 = (const float*)d_in[18];
    const float* bn_g  = (const float*)d_in[19];
    const float* bn_b  = (const float*)d_in[20];
    const float* bn_vg = (const float*)d_in[21];
    const float* eu_lin = (const float*)d_in[22];
    const float* eu_w1 = (const float*)d_in[23];
    const float* eu_b1 = (const float*)d_in[24];
    const float* eu_w2 = (const float*)d_in[25];
    const float* eu_b2 = (const float*)d_in[26];
    const float* eu_w3 = (const float*)d_in[27];
    const float* eu_b3 = (const float*)d_in[28];
    const float* eu_ln_g = (const float*)d_in[29];
    const float* eu_ln_b = (const float*)d_in[30];
    const float* mu_w = (const float*)d_in[31];
    const float* mu_b = (const float*)d_in[32];
    const float* lv_w = (const float*)d_in[33];
    const float* lv_b = (const float*)d_in[34];

    char* ws = (char*)d_ws;
    size_t off = 0;
    auto alloc = [&](size_t bytes) -> void* {
        void* p = ws + off;
        off += (bytes + 255) & ~(size_t)255;
        return p;
    };
    bf16*  ef_b  = (bf16*) alloc((size_t)NE * CZ * 2);     // residual stream
    bf16*  buf_a = (bf16*) alloc((size_t)NE * CZ * 2);
    float* xs    = (float*)alloc((size_t)NN * CS * 4);
    float* xv    = (float*)alloc((size_t)NN * 24 * 4);
    float* ags   = (float*)alloc((size_t)NN * CS * 4);
    float* agv   = (float*)alloc((size_t)NN * 24 * 4);
    int*   cnti  = (int*)  alloc((size_t)NN * 4);
    float* icnt  = (float*)alloc((size_t)NN * 4);
    bf16*  a_b   = (bf16*) alloc((size_t)NN * CZ * 2);
    bf16* ee_w1t = (bf16*)alloc((size_t)INZ * CZ * 2);
    bf16* ee_w2t = (bf16*)alloc((size_t)CZ * CZ * 2);
    bf16* ee_w3t = (bf16*)alloc((size_t)CZ * CZ * 2);
    bf16* fc_w1t = (bf16*)alloc((size_t)NL * CZ * CZ * 2);
    bf16* fc_w2t = (bf16*)alloc((size_t)NL * WN * CZ * 2);
    bf16* eu_w1t = (bf16*)alloc((size_t)NL * 384 * CZ * 2);
    bf16* eu_w2t = (bf16*)alloc((size_t)NL * CZ * CZ * 2);
    bf16* eu_w3t = (bf16*)alloc((size_t)NL * CZ * CZ * 2);

    const int TRN = INZ*CZ + 2*CZ*CZ + NL*CZ*CZ + NL*CZ*WN + NL*384*CZ + 2*NL*CZ*CZ;
    transpose_all<<<(TRN + 255) / 256, 256, 0, stream>>>(
        ee_w1, ee_w2, ee_w3, fc_w1, fc_w2, eu_w1, eu_w2, eu_w3,
        ee_w1t, ee_w2t, ee_w3t, fc_w1t, fc_w2t, eu_w1t, eu_w2t, eu_w3t);

    node_embed<<<NN, 64, 0, stream>>>(node_raw, ne_ws, ne_wv, xs, xv);
    hipMemsetAsync(cnti, 0, NN * 4, stream);
    count_src<<<NE / 256, 256, 0, stream>>>(ei, cnti);
    init_misc<<<(NN * CS) / 256, 256, 0, stream>>>(cnti, icnt, ags, agv);

    const int GE = NE / 64;   // 480
    // edge embedding: ee1 (K=1664 fp32 A) then fused ee2+ee3+LN
    gemm64<1, 1, 0><<<GE, 256, 0, stream>>>(edge_raw, ee_w1t, ee_b1, buf_a, NE, INZ, nullptr, nullptr, nullptr);
    mlp2<0><<<GE, 256, 0, stream>>>(buf_a, ee_w2t, ee_b2, ee_w3t, ee_b3, ee_ln_g, ee_ln_b, ef_b);

    for (int l = 0; l < NL; l++) {
        fc2_tp<<<NE / 16, 256, 0, stream>>>(
            ef_b, fc_w1t + (size_t)l * CZ * CZ, fc_b1 + l * CZ,
            fc_w2t + (size_t)l * WN * CZ, fc_b2 + l * WN,
            ei, edge_vecs, xs, xv, icnt, ags, agv);
        bnfused<<<40, 256, 0, stream>>>(xs, xv, ags, agv,
                                        bn_g + l * CS, bn_b + l * CS, bn_vg + l * CV);
        lin_a<<<NN, 128, 0, stream>>>(xs, eu_lin + (size_t)l * CS * CZ, a_b);
        gemm64<1, 0, 1><<<GE, 256, 0, stream>>>(
            nullptr, eu_w1t + (size_t)l * 384 * CZ, eu_b1 + l * CZ, buf_a, NE, 384, a_b, ef_b, ei);
        mlp2<1><<<GE, 256, 0, stream>>>(buf_a, eu_w2t + (size_t)l * CZ * CZ, eu_b2 + l * CZ,
                                        eu_w3t + (size_t)l * CZ * CZ, eu_b3 + l * CZ,
                                        eu_ln_g + l * CZ, eu_ln_b + l * CZ, ef_b);
    }

    final_out<<<NN, 128, 0, stream>>>(xs, xv, rot, mu_w, mu_b, lv_w, lv_b, (float*)d_out);
}